// Round 5
// baseline (234.761 us; speedup 1.0000x reference)
//
#include <hip/hip_runtime.h>
#include <hip/hip_bf16.h>

// LocalKNN: B=64, Way=5, D=64, Nq=1024, Ns=1024, K=3.
// out[b,w] = sum_q rnq[q] * sum(top3_s( <q_bq, shat_bws> ))
// Round 5: 8 q-tiles per wave (2x MFMA+INS work per s-tile load, half the
// load stream), 3-deep ring prefetch, bijective XCD swizzle (640 = 8*80).

using bf16x8 = __attribute__((ext_vector_type(8))) short;  // 8 bf16 = 4 VGPRs
using f32x4  = __attribute__((ext_vector_type(4))) float;

__device__ inline unsigned cvt_pk_bf16(float lo, float hi) {
    unsigned r;
    asm("v_cvt_pk_bf16_f32 %0, %1, %2" : "=v"(r) : "v"(lo), "v"(hi));
    return r;
}

__device__ inline uint4 pack8cvt(const float* v) {
    uint4 r;
    r.x = cvt_pk_bf16(v[0], v[1]);
    r.y = cvt_pk_bf16(v[2], v[3]);
    r.z = cvt_pk_bf16(v[4], v[5]);
    r.w = cvt_pk_bf16(v[6], v[7]);
    return r;
}

// branchless insert of v into sorted top-3 (t0>=t1>=t2): 1 max + 2 med3
#define INS(v, T0, T1, T2) do {                         \
    float _v = (v);                                     \
    float _n0 = fmaxf((T0), _v);                        \
    float _n1 = __builtin_amdgcn_fmed3f(_v, (T0), (T1));\
    float _n2 = __builtin_amdgcn_fmed3f(_v, (T1), (T2));\
    (T0) = _n0; (T1) = _n1; (T2) = _n2;                 \
} while (0)

// ============================= fast path =====================================
// Fragment layout: per 16-col tile, 128 uint4 slots; slot h*16 + r holds
// column (tile*16+r)'s elements d = 8h..8h+7 as 4 packed bf16-pairs.
// MFMA read: slot c*64 + lane -> lane holds col r=lane&15, k = c*32 + (lane>>4)*8 + j.

// ---- prep_all: raw Q/S -> bf16 fragments (+ rnq) ----------------------------
__global__ __launch_bounds__(256) void prep_all(const float* __restrict__ Q,
                                                const float* __restrict__ S,
                                                uint4* __restrict__ Qbf,
                                                uint4* __restrict__ Sbf,
                                                float* __restrict__ rnq) {
    const int blk = blockIdx.x;
    if (blk < 256) {
        const int b = blk >> 2;
        const int col = ((blk & 3) << 8) + threadIdx.x;      // q in 0..1023
        const float* p = Q + (size_t)b * 65536 + col;
        float v[64];
        #pragma unroll
        for (int d = 0; d < 64; ++d) v[d] = p[(size_t)d << 10];
        float ss = 0.f;
        #pragma unroll
        for (int d = 0; d < 64; ++d) ss += v[d] * v[d];
        rnq[(b << 10) + col] = 1.0f / fmaxf(sqrtf(ss), 1e-12f);
        uint4* ob = Qbf + ((size_t)(b << 6) + (col >> 4)) * 128 + (col & 15);
        #pragma unroll
        for (int h = 0; h < 8; ++h)
            ob[h << 4] = pack8cvt(&v[h << 3]);
    } else {
        const int bw = (blk - 256) >> 2;
        const int col = ((blk & 3) << 8) + threadIdx.x;      // s in 0..1023
        const float* p = S + (size_t)bw * 65536 + col;
        float v[64];
        #pragma unroll
        for (int d = 0; d < 64; ++d) v[d] = p[(size_t)d << 10];
        float ss = 0.f;
        #pragma unroll
        for (int d = 0; d < 64; ++d) ss += v[d] * v[d];
        const float rs = 1.0f / fmaxf(sqrtf(ss), 1e-12f);
        #pragma unroll
        for (int d = 0; d < 64; ++d) v[d] *= rs;
        uint4* ob = Sbf + ((size_t)(bw << 6) + (col >> 4)) * 128 + (col & 15);
        #pragma unroll
        for (int h = 0; h < 8; ++h)
            ob[h << 4] = pack8cvt(&v[h << 3]);
    }
}

// ---- main: barrier-free fused GEMM + top-3 ---------------------------------
// 1-D grid 640 (logical l: qc = l&1, bw = l>>1), block = 256 (4 waves).
// Wave wv holds 8 q-tiles (tiles qc*32 + wv*8 + {0..7}) in registers and
// streams all 64 s-tiles: 16 MFMA + 96 VALU per 2 loads.
__global__ __launch_bounds__(256, 3) void knn_main(const uint4* __restrict__ Qbf,
                                                   const uint4* __restrict__ Sbf,
                                                   const float* __restrict__ rnq,
                                                   float* __restrict__ partial) {
    __shared__ float wsum[4];
    const int lin = blockIdx.x;
    const int l   = (lin & 7) * 80 + (lin >> 3);     // 640 = 8*80, bijective
    const int qc  = l & 1;
    const int bw  = l >> 1;                          // b*5 + w
    const int b   = bw / 5;
    const int wv = threadIdx.x >> 6, lane = threadIdx.x & 63;

    const uint4* qb = Qbf + ((size_t)(b << 6) + (qc << 5) + (wv << 3)) * 128 + lane;
    bf16x8 bq[8][2];
    #pragma unroll
    for (int qt = 0; qt < 8; ++qt)
        #pragma unroll
        for (int c = 0; c < 2; ++c)
            bq[qt][c] = *reinterpret_cast<const bf16x8*>(&qb[qt * 128 + (c << 6)]);

    const uint4* sb = Sbf + (size_t)(bw << 6) * 128 + lane;

    float t0[8], t1[8], t2[8];
    #pragma unroll
    for (int qt = 0; qt < 8; ++qt) { t0[qt] = -1e30f; t1[qt] = -1e30f; t2[qt] = -1e30f; }

    // 3-deep ring prefetch: load directly into the slot consumed 3 iters later.
    bf16x8 abuf[4][2];
    #pragma unroll
    for (int i = 0; i < 3; ++i) {
        abuf[i][0] = *reinterpret_cast<const bf16x8*>(&sb[i * 128]);
        abuf[i][1] = *reinterpret_cast<const bf16x8*>(&sb[i * 128 + 64]);
    }
    #pragma unroll 4
    for (int st = 0; st < 64; ++st) {
        if (st + 3 < 64) {
            abuf[(st + 3) & 3][0] = *reinterpret_cast<const bf16x8*>(&sb[(st + 3) * 128]);
            abuf[(st + 3) & 3][1] = *reinterpret_cast<const bf16x8*>(&sb[(st + 3) * 128 + 64]);
        }
        #pragma unroll
        for (int qt = 0; qt < 8; ++qt) {
            f32x4 c = {0.f, 0.f, 0.f, 0.f};
            c = __builtin_amdgcn_mfma_f32_16x16x32_bf16(abuf[st & 3][0], bq[qt][0], c, 0, 0, 0);
            c = __builtin_amdgcn_mfma_f32_16x16x32_bf16(abuf[st & 3][1], bq[qt][1], c, 0, 0, 0);
            #pragma unroll
            for (int j = 0; j < 4; ++j)
                INS(c[j], t0[qt], t1[qt], t2[qt]);
        }
    }

    // merge top-3 across the 4 lane-groups sharing each q; apply rnq
    float s3 = 0.f;
    #pragma unroll
    for (int qt = 0; qt < 8; ++qt) {
        #pragma unroll
        for (int m = 16; m <= 32; m <<= 1) {
            float b0 = __shfl_xor(t0[qt], m);
            float b1 = __shfl_xor(t1[qt], m);
            float b2 = __shfl_xor(t2[qt], m);
            INS(b0, t0[qt], t1[qt], t2[qt]);
            INS(b1, t0[qt], t1[qt], t2[qt]);
            INS(b2, t0[qt], t1[qt], t2[qt]);
        }
        const int qg = (qc << 9) + (wv << 7) + (qt << 4) + (lane & 15);
        s3 += (t0[qt] + t1[qt] + t2[qt]) * rnq[(b << 10) + qg];
    }
    #pragma unroll
    for (int m = 1; m < 64; m <<= 1) s3 += __shfl_xor(s3, m);
    s3 *= 0.25f;                       // each q replicated over 4 lane-groups
    if (lane == 0) wsum[wv] = s3;
    __syncthreads();
    if (threadIdx.x == 0)
        partial[((size_t)bw << 1) + qc] = (wsum[0] + wsum[1]) + (wsum[2] + wsum[3]);
}

__global__ void finalize2(const float* __restrict__ partial, float* __restrict__ out) {
    int i = blockIdx.x * blockDim.x + threadIdx.x;
    if (i < 320)
        out[i] = partial[2 * i] + partial[2 * i + 1];
}

// ============================ fallback path (round-2) ========================
__global__ void norms_kernel(const float* __restrict__ Q, const float* __restrict__ S,
                             float* __restrict__ rnq, float* __restrict__ rns) {
    int gid = blockIdx.x * blockDim.x + threadIdx.x;
    if (gid < 65536) {
        int b = gid >> 10, qi = gid & 1023;
        const float* p = Q + (size_t)b * 65536 + qi;
        float ss = 0.f;
        #pragma unroll
        for (int d = 0; d < 64; ++d) { float v = p[(size_t)d * 1024]; ss += v * v; }
        rnq[gid] = 1.0f / fmaxf(sqrtf(ss), 1e-12f);
    } else {
        int v = gid - 65536;
        int bw = v >> 10, si = v & 1023;
        const float* p = S + (size_t)bw * 65536 + si;
        float ss = 0.f;
        #pragma unroll
        for (int d = 0; d < 64; ++d) { float x = p[(size_t)d * 1024]; ss += x * x; }
        rns[v] = 1.0f / fmaxf(sqrtf(ss), 1e-12f);
    }
}

__global__ __launch_bounds__(512, 4) void knn_fb(
        const float* __restrict__ Q, const float* __restrict__ S,
        const float* __restrict__ rnq, const float* __restrict__ rns,
        float* __restrict__ partial) {
    __shared__ uint4 qfrag[16 * 128];
    __shared__ uint4 sfrag[2][4 * 128];
    __shared__ float wsum[8];

    const int qc = blockIdx.x, w = blockIdx.y, b = blockIdx.z;
    const int t = threadIdx.x, wv = t >> 6, lane = t & 63;

    const float* Qb   = Q + (size_t)b * 65536;
    const float* Sb   = S + (size_t)(b * 5 + w) * 65536;
    const float* rnqb = rnq + (b << 10);
    const float* rnsb = rns + ((b * 5 + w) << 10);

    bf16x8 bq[4][2];
    for (int ph = 0; ph < 2; ++ph) {
        for (int sub = 0; sub < 4; ++sub) {
            int qg = (qc << 9) + (ph << 8) + (sub << 6) + lane;
            float v[8];
            #pragma unroll
            for (int i = 0; i < 8; ++i)
                v[i] = Qb[(size_t)((wv << 3) + i) * 1024 + qg];
            qfrag[((sub << 2) + (lane >> 4)) * 128 + (wv << 4) + (lane & 15)] = pack8cvt(v);
        }
        __syncthreads();
        if ((wv >> 2) == ph) {
            #pragma unroll
            for (int qt = 0; qt < 4; ++qt)
                #pragma unroll
                for (int c = 0; c < 2; ++c)
                    bq[qt][c] = *reinterpret_cast<const bf16x8*>(
                        &qfrag[(((wv & 3) << 2) + qt) * 128 + (c << 6) + lane]);
        }
        __syncthreads();
    }

    {
        float sv[8]; float rs = rnsb[lane];
        #pragma unroll
        for (int i = 0; i < 8; ++i)
            sv[i] = Sb[(size_t)((wv << 3) + i) * 1024 + lane] * rs;
        sfrag[0][(lane >> 4) * 128 + (wv << 4) + (lane & 15)] = pack8cvt(sv);
    }
    __syncthreads();

    float t0[4], t1[4], t2[4];
    #pragma unroll
    for (int qt = 0; qt < 4; ++qt) { t0[qt] = -1e30f; t1[qt] = -1e30f; t2[qt] = -1e30f; }
    int cur = 0;
    const float* sp = Sb + ((wv << 3) << 10) + lane;

    for (int blk = 0; blk < 16; ++blk) {
        float sv[8]; float rs;
        if (blk < 15) {
            const int sb_ = (blk + 1) << 6;
            rs = rnsb[sb_ + lane];
            #pragma unroll
            for (int i = 0; i < 8; ++i)
                sv[i] = sp[(size_t)(i << 10) + sb_];
        }
        #pragma unroll
        for (int st = 0; st < 4; ++st) {
            bf16x8 a0 = *reinterpret_cast<const bf16x8*>(&sfrag[cur][st * 128 + lane]);
            bf16x8 a1 = *reinterpret_cast<const bf16x8*>(&sfrag[cur][st * 128 + 64 + lane]);
            #pragma unroll
            for (int qt = 0; qt < 4; ++qt) {
                f32x4 c = {0.f, 0.f, 0.f, 0.f};
                c = __builtin_amdgcn_mfma_f32_16x16x32_bf16(a0, bq[qt][0], c, 0, 0, 0);
                c = __builtin_amdgcn_mfma_f32_16x16x32_bf16(a1, bq[qt][1], c, 0, 0, 0);
                #pragma unroll
                for (int j = 0; j < 4; ++j)
                    INS(c[j], t0[qt], t1[qt], t2[qt]);
            }
        }
        if (blk < 15) {
            #pragma unroll
            for (int i = 0; i < 8; ++i) sv[i] *= rs;
            sfrag[cur ^ 1][(lane >> 4) * 128 + (wv << 4) + (lane & 15)] = pack8cvt(sv);
        }
        __syncthreads();
        cur ^= 1;
    }

    float s3 = 0.f;
    #pragma unroll
    for (int qt = 0; qt < 4; ++qt) {
        #pragma unroll
        for (int m = 16; m <= 32; m <<= 1) {
            float b0 = __shfl_xor(t0[qt], m);
            float b1 = __shfl_xor(t1[qt], m);
            float b2 = __shfl_xor(t2[qt], m);
            INS(b0, t0[qt], t1[qt], t2[qt]);
            INS(b1, t0[qt], t1[qt], t2[qt]);
            INS(b2, t0[qt], t1[qt], t2[qt]);
        }
        int qg = (qc << 9) + (wv << 6) + (qt << 4) + (lane & 15);
        s3 += (t0[qt] + t1[qt] + t2[qt]) * rnqb[qg];
    }
    #pragma unroll
    for (int m = 1; m < 64; m <<= 1) s3 += __shfl_xor(s3, m);
    s3 *= 0.25f;
    if (lane == 0) wsum[wv] = s3;
    __syncthreads();
    if (t == 0) {
        float acc = 0.f;
        #pragma unroll
        for (int i = 0; i < 8; ++i) acc += wsum[i];
        partial[((b * 5 + w) << 1) + qc] = acc;
    }
}

// =============================================================================
extern "C" void kernel_launch(void* const* d_in, const int* in_sizes, int n_in,
                              void* d_out, int out_size, void* d_ws, size_t ws_size,
                              hipStream_t stream) {
    const float* Q = (const float*)d_in[0];   // (64,64,32,32)
    const float* S = (const float*)d_in[1];   // (64,5,64,1024)
    float* out = (float*)d_out;               // (64,5)

    // fast-path ws layout: Qbf 8 MB | Sbf 41.9 MB | rnq 256 KB | partial 5 KB
    const size_t NEED = 8388608ull + 41943040ull + 262144ull + 5120ull;
    if (ws_size >= NEED) {
        uint4* Qbf    = (uint4*)d_ws;
        uint4* Sbf    = (uint4*)((char*)d_ws + 8388608ull);
        float* rnq    = (float*)((char*)d_ws + 8388608ull + 41943040ull);
        float* partial= (float*)((char*)d_ws + 8388608ull + 41943040ull + 262144ull);
        prep_all<<<1536, 256, 0, stream>>>(Q, S, Qbf, Sbf, rnq);
        knn_main<<<640, 256, 0, stream>>>(Qbf, Sbf, rnq, partial);
        finalize2<<<2, 256, 0, stream>>>(partial, out);
    } else {
        float* rnq = (float*)d_ws;
        float* rns = rnq + 65536;
        float* partial = rns + 327680;
        norms_kernel<<<(65536 + 327680) / 256, 256, 0, stream>>>(Q, S, rnq, rns);
        knn_fb<<<dim3(2, 5, 64), 512, 0, stream>>>(Q, S, rnq, rns, partial);
        finalize2<<<2, 256, 0, stream>>>(partial, out);
    }
}

// Round 6
// 99.205 us; speedup vs baseline: 2.3664x; 2.3664x over previous
//
#include <hip/hip_runtime.h>
#include <hip/hip_bf16.h>

// LocalKNN: B=64, Way=5, D=64, Nq=1024, Ns=1024, K=3.
// out[b,w] = sum_q rnq[q] * sum(top3_s( <q_bq, shat_bws> ))
// Round 6: revert to 4 q-tiles/wave (round-5's 8-tile variant spilled: VGPR 84
// + 41 MB scratch WRITE). Add s-split x2 (top-3 is mergeable) -> 2560 blocks,
// ~5 resident blocks/CU for wave-level latency hiding. Per-q top3 triples go
// to ws; a merge kernel combines halves, applies rnq, reduces to out.

using bf16x8 = __attribute__((ext_vector_type(8))) short;  // 8 bf16 = 4 VGPRs
using f32x4  = __attribute__((ext_vector_type(4))) float;

__device__ inline unsigned cvt_pk_bf16(float lo, float hi) {
    unsigned r;
    asm("v_cvt_pk_bf16_f32 %0, %1, %2" : "=v"(r) : "v"(lo), "v"(hi));
    return r;
}

__device__ inline uint4 pack8cvt(const float* v) {
    uint4 r;
    r.x = cvt_pk_bf16(v[0], v[1]);
    r.y = cvt_pk_bf16(v[2], v[3]);
    r.z = cvt_pk_bf16(v[4], v[5]);
    r.w = cvt_pk_bf16(v[6], v[7]);
    return r;
}

// branchless insert of v into sorted top-3 (t0>=t1>=t2): 1 max + 2 med3
#define INS(v, T0, T1, T2) do {                         \
    float _v = (v);                                     \
    float _n0 = fmaxf((T0), _v);                        \
    float _n1 = __builtin_amdgcn_fmed3f(_v, (T0), (T1));\
    float _n2 = __builtin_amdgcn_fmed3f(_v, (T1), (T2));\
    (T0) = _n0; (T1) = _n1; (T2) = _n2;                 \
} while (0)

// ============================= fast path =====================================
// Fragment layout: per 16-col tile, 128 uint4 slots; slot h*16 + r holds
// column (tile*16+r)'s elements d = 8h..8h+7 as 4 packed bf16-pairs.
// MFMA read: slot c*64 + lane -> lane holds col r=lane&15, k = c*32 + (lane>>4)*8 + j.

// ---- prep_all: raw Q/S -> bf16 fragments (+ rnq) ----------------------------
__global__ __launch_bounds__(256) void prep_all(const float* __restrict__ Q,
                                                const float* __restrict__ S,
                                                uint4* __restrict__ Qbf,
                                                uint4* __restrict__ Sbf,
                                                float* __restrict__ rnq) {
    const int blk = blockIdx.x;
    if (blk < 256) {
        const int b = blk >> 2;
        const int col = ((blk & 3) << 8) + threadIdx.x;      // q in 0..1023
        const float* p = Q + (size_t)b * 65536 + col;
        float v[64];
        #pragma unroll
        for (int d = 0; d < 64; ++d) v[d] = p[(size_t)d << 10];
        float ss = 0.f;
        #pragma unroll
        for (int d = 0; d < 64; ++d) ss += v[d] * v[d];
        rnq[(b << 10) + col] = 1.0f / fmaxf(sqrtf(ss), 1e-12f);
        uint4* ob = Qbf + ((size_t)(b << 6) + (col >> 4)) * 128 + (col & 15);
        #pragma unroll
        for (int h = 0; h < 8; ++h)
            ob[h << 4] = pack8cvt(&v[h << 3]);
    } else {
        const int bw = (blk - 256) >> 2;
        const int col = ((blk & 3) << 8) + threadIdx.x;      // s in 0..1023
        const float* p = S + (size_t)bw * 65536 + col;
        float v[64];
        #pragma unroll
        for (int d = 0; d < 64; ++d) v[d] = p[(size_t)d << 10];
        float ss = 0.f;
        #pragma unroll
        for (int d = 0; d < 64; ++d) ss += v[d] * v[d];
        const float rs = 1.0f / fmaxf(sqrtf(ss), 1e-12f);
        #pragma unroll
        for (int d = 0; d < 64; ++d) v[d] *= rs;
        uint4* ob = Sbf + ((size_t)(bw << 6) + (col >> 4)) * 128 + (col & 15);
        #pragma unroll
        for (int h = 0; h < 8; ++h)
            ob[h << 4] = pack8cvt(&v[h << 3]);
    }
}

// ---- main: barrier-free fused GEMM + top-3 (s-split x2) ---------------------
// 1-D grid 2560. logical l = bw*8 + qc*2 + half; XCD swizzle l = (lin&7)*320 + lin>>3
// so the 8 blocks sharing one (b,w) S-slice live on one XCD's L2.
// block = 256 (4 waves); wave wv holds q-tiles qc*16+wv*4+{0..3} in registers,
// streams s-tiles [half*32, half*32+32). Writes per-q top3 triple to P0/P1/P2.
__global__ __launch_bounds__(256) void knn_main(const uint4* __restrict__ Qbf,
                                                const uint4* __restrict__ Sbf,
                                                float* __restrict__ P0,
                                                float* __restrict__ P1,
                                                float* __restrict__ P2) {
    const int lin  = blockIdx.x;
    const int l    = (lin & 7) * 320 + (lin >> 3);   // 2560 = 8*320, bijective
    const int half = l & 1;
    const int qc   = (l >> 1) & 3;
    const int bw   = l >> 3;                          // b*5 + w
    const int b    = bw / 5;
    const int wv = threadIdx.x >> 6, lane = threadIdx.x & 63;

    const uint4* qb = Qbf + ((size_t)(b << 6) + (qc << 4) + (wv << 2)) * 128 + lane;
    bf16x8 bq[4][2];
    #pragma unroll
    for (int qt = 0; qt < 4; ++qt)
        #pragma unroll
        for (int c = 0; c < 2; ++c)
            bq[qt][c] = *reinterpret_cast<const bf16x8*>(&qb[qt * 128 + (c << 6)]);

    const uint4* sb = Sbf + ((size_t)(bw << 6) + (half << 5)) * 128 + lane;

    float t0[4], t1[4], t2[4];
    #pragma unroll
    for (int qt = 0; qt < 4; ++qt) { t0[qt] = -1e30f; t1[qt] = -1e30f; t2[qt] = -1e30f; }

    // 3-deep ring prefetch over this block's 32 s-tiles
    bf16x8 abuf[4][2];
    #pragma unroll
    for (int i = 0; i < 3; ++i) {
        abuf[i][0] = *reinterpret_cast<const bf16x8*>(&sb[i * 128]);
        abuf[i][1] = *reinterpret_cast<const bf16x8*>(&sb[i * 128 + 64]);
    }
    #pragma unroll 4
    for (int st = 0; st < 32; ++st) {
        if (st + 3 < 32) {
            abuf[(st + 3) & 3][0] = *reinterpret_cast<const bf16x8*>(&sb[(st + 3) * 128]);
            abuf[(st + 3) & 3][1] = *reinterpret_cast<const bf16x8*>(&sb[(st + 3) * 128 + 64]);
        }
        #pragma unroll
        for (int qt = 0; qt < 4; ++qt) {
            f32x4 c = {0.f, 0.f, 0.f, 0.f};
            c = __builtin_amdgcn_mfma_f32_16x16x32_bf16(abuf[st & 3][0], bq[qt][0], c, 0, 0, 0);
            c = __builtin_amdgcn_mfma_f32_16x16x32_bf16(abuf[st & 3][1], bq[qt][1], c, 0, 0, 0);
            #pragma unroll
            for (int j = 0; j < 4; ++j)
                INS(c[j], t0[qt], t1[qt], t2[qt]);
        }
    }

    // merge top-3 across the 4 lane-groups sharing each q
    #pragma unroll
    for (int qt = 0; qt < 4; ++qt) {
        #pragma unroll
        for (int m = 16; m <= 32; m <<= 1) {
            float b0 = __shfl_xor(t0[qt], m);
            float b1 = __shfl_xor(t1[qt], m);
            float b2 = __shfl_xor(t2[qt], m);
            INS(b0, t0[qt], t1[qt], t2[qt]);
            INS(b1, t0[qt], t1[qt], t2[qt]);
            INS(b2, t0[qt], t1[qt], t2[qt]);
        }
    }
    // lane-group 0 writes the triples (all 4 groups identical)
    if (lane < 16) {
        const size_t e0 = (size_t)bw * 2048 + (half << 10) + (qc << 8) + (wv << 6) + lane;
        #pragma unroll
        for (int qt = 0; qt < 4; ++qt) {
            P0[e0 + (qt << 4)] = t0[qt];
            P1[e0 + (qt << 4)] = t1[qt];
            P2[e0 + (qt << 4)] = t2[qt];
        }
    }
}

// ---- merge: combine the 2 s-halves, apply rnq, reduce over q ----------------
// grid = 320 (one block per bw), block = 1024 (16 waves).
__global__ __launch_bounds__(1024) void knn_merge(const float* __restrict__ P0,
                                                  const float* __restrict__ P1,
                                                  const float* __restrict__ P2,
                                                  const float* __restrict__ rnq,
                                                  float* __restrict__ out) {
    __shared__ float wsum[16];
    const int bw = blockIdx.x;
    const int q  = threadIdx.x;
    const int b  = bw / 5;
    const size_t e = (size_t)bw * 2048 + q;

    float t0 = P0[e], t1 = P1[e], t2 = P2[e];
    float u0 = P0[e + 1024], u1 = P1[e + 1024], u2 = P2[e + 1024];
    INS(u0, t0, t1, t2);
    INS(u1, t0, t1, t2);
    INS(u2, t0, t1, t2);
    float s = (t0 + t1 + t2) * rnq[(b << 10) + q];

    #pragma unroll
    for (int m = 1; m < 64; m <<= 1) s += __shfl_xor(s, m);
    if ((q & 63) == 0) wsum[q >> 6] = s;
    __syncthreads();
    if (q < 16) {
        float v = wsum[q];
        #pragma unroll
        for (int m = 1; m < 16; m <<= 1) v += __shfl_xor(v, m);
        if (q == 0) out[bw] = v;
    }
}

// ============================ fallback path (round-2) ========================
__global__ void norms_kernel(const float* __restrict__ Q, const float* __restrict__ S,
                             float* __restrict__ rnq, float* __restrict__ rns) {
    int gid = blockIdx.x * blockDim.x + threadIdx.x;
    if (gid < 65536) {
        int b = gid >> 10, qi = gid & 1023;
        const float* p = Q + (size_t)b * 65536 + qi;
        float ss = 0.f;
        #pragma unroll
        for (int d = 0; d < 64; ++d) { float v = p[(size_t)d * 1024]; ss += v * v; }
        rnq[gid] = 1.0f / fmaxf(sqrtf(ss), 1e-12f);
    } else {
        int v = gid - 65536;
        int bw = v >> 10, si = v & 1023;
        const float* p = S + (size_t)bw * 65536 + si;
        float ss = 0.f;
        #pragma unroll
        for (int d = 0; d < 64; ++d) { float x = p[(size_t)d * 1024]; ss += x * x; }
        rns[v] = 1.0f / fmaxf(sqrtf(ss), 1e-12f);
    }
}

__global__ __launch_bounds__(512, 4) void knn_fb(
        const float* __restrict__ Q, const float* __restrict__ S,
        const float* __restrict__ rnq, const float* __restrict__ rns,
        float* __restrict__ partial) {
    __shared__ uint4 qfrag[16 * 128];
    __shared__ uint4 sfrag[2][4 * 128];
    __shared__ float wsum[8];

    const int qc = blockIdx.x, w = blockIdx.y, b = blockIdx.z;
    const int t = threadIdx.x, wv = t >> 6, lane = t & 63;

    const float* Qb   = Q + (size_t)b * 65536;
    const float* Sb   = S + (size_t)(b * 5 + w) * 65536;
    const float* rnqb = rnq + (b << 10);
    const float* rnsb = rns + ((b * 5 + w) << 10);

    bf16x8 bq[4][2];
    for (int ph = 0; ph < 2; ++ph) {
        for (int sub = 0; sub < 4; ++sub) {
            int qg = (qc << 9) + (ph << 8) + (sub << 6) + lane;
            float v[8];
            #pragma unroll
            for (int i = 0; i < 8; ++i)
                v[i] = Qb[(size_t)((wv << 3) + i) * 1024 + qg];
            qfrag[((sub << 2) + (lane >> 4)) * 128 + (wv << 4) + (lane & 15)] = pack8cvt(v);
        }
        __syncthreads();
        if ((wv >> 2) == ph) {
            #pragma unroll
            for (int qt = 0; qt < 4; ++qt)
                #pragma unroll
                for (int c = 0; c < 2; ++c)
                    bq[qt][c] = *reinterpret_cast<const bf16x8*>(
                        &qfrag[(((wv & 3) << 2) + qt) * 128 + (c << 6) + lane]);
        }
        __syncthreads();
    }

    {
        float sv[8]; float rs = rnsb[lane];
        #pragma unroll
        for (int i = 0; i < 8; ++i)
            sv[i] = Sb[(size_t)((wv << 3) + i) * 1024 + lane] * rs;
        sfrag[0][(lane >> 4) * 128 + (wv << 4) + (lane & 15)] = pack8cvt(sv);
    }
    __syncthreads();

    float t0[4], t1[4], t2[4];
    #pragma unroll
    for (int qt = 0; qt < 4; ++qt) { t0[qt] = -1e30f; t1[qt] = -1e30f; t2[qt] = -1e30f; }
    int cur = 0;
    const float* sp = Sb + ((wv << 3) << 10) + lane;

    for (int blk = 0; blk < 16; ++blk) {
        float sv[8]; float rs;
        if (blk < 15) {
            const int sb_ = (blk + 1) << 6;
            rs = rnsb[sb_ + lane];
            #pragma unroll
            for (int i = 0; i < 8; ++i)
                sv[i] = sp[(size_t)(i << 10) + sb_];
        }
        #pragma unroll
        for (int st = 0; st < 4; ++st) {
            bf16x8 a0 = *reinterpret_cast<const bf16x8*>(&sfrag[cur][st * 128 + lane]);
            bf16x8 a1 = *reinterpret_cast<const bf16x8*>(&sfrag[cur][st * 128 + 64 + lane]);
            #pragma unroll
            for (int qt = 0; qt < 4; ++qt) {
                f32x4 c = {0.f, 0.f, 0.f, 0.f};
                c = __builtin_amdgcn_mfma_f32_16x16x32_bf16(a0, bq[qt][0], c, 0, 0, 0);
                c = __builtin_amdgcn_mfma_f32_16x16x32_bf16(a1, bq[qt][1], c, 0, 0, 0);
                #pragma unroll
                for (int j = 0; j < 4; ++j)
                    INS(c[j], t0[qt], t1[qt], t2[qt]);
            }
        }
        if (blk < 15) {
            #pragma unroll
            for (int i = 0; i < 8; ++i) sv[i] *= rs;
            sfrag[cur ^ 1][(lane >> 4) * 128 + (wv << 4) + (lane & 15)] = pack8cvt(sv);
        }
        __syncthreads();
        cur ^= 1;
    }

    float s3 = 0.f;
    #pragma unroll
    for (int qt = 0; qt < 4; ++qt) {
        #pragma unroll
        for (int m = 16; m <= 32; m <<= 1) {
            float b0 = __shfl_xor(t0[qt], m);
            float b1 = __shfl_xor(t1[qt], m);
            float b2 = __shfl_xor(t2[qt], m);
            INS(b0, t0[qt], t1[qt], t2[qt]);
            INS(b1, t0[qt], t1[qt], t2[qt]);
            INS(b2, t0[qt], t1[qt], t2[qt]);
        }
        int qg = (qc << 9) + (wv << 6) + (qt << 4) + (lane & 15);
        s3 += (t0[qt] + t1[qt] + t2[qt]) * rnqb[qg];
    }
    #pragma unroll
    for (int m = 1; m < 64; m <<= 1) s3 += __shfl_xor(s3, m);
    s3 *= 0.25f;
    if (lane == 0) wsum[wv] = s3;
    __syncthreads();
    if (t == 0) {
        float acc = 0.f;
        #pragma unroll
        for (int i = 0; i < 8; ++i) acc += wsum[i];
        partial[((b * 5 + w) << 1) + qc] = acc;
    }
}

__global__ void finalize2(const float* __restrict__ partial, float* __restrict__ out) {
    int i = blockIdx.x * blockDim.x + threadIdx.x;
    if (i < 320)
        out[i] = partial[2 * i] + partial[2 * i + 1];
}

// =============================================================================
extern "C" void kernel_launch(void* const* d_in, const int* in_sizes, int n_in,
                              void* d_out, int out_size, void* d_ws, size_t ws_size,
                              hipStream_t stream) {
    const float* Q = (const float*)d_in[0];   // (64,64,32,32)
    const float* S = (const float*)d_in[1];   // (64,5,64,1024)
    float* out = (float*)d_out;               // (64,5)

    // fast-path ws: Qbf 8MB | Sbf 41.9MB | rnq 256KB | P0/P1/P2 3x2.62MB  (~58.5MB)
    const size_t QBF = 8388608ull, SBF = 41943040ull, RNQ = 262144ull, PL = 2621440ull;
    const size_t NEED = QBF + SBF + RNQ + 3 * PL;
    if (ws_size >= NEED) {
        char* base = (char*)d_ws;
        uint4* Qbf = (uint4*)base;
        uint4* Sbf = (uint4*)(base + QBF);
        float* rnq = (float*)(base + QBF + SBF);
        float* P0  = (float*)(base + QBF + SBF + RNQ);
        float* P1  = (float*)(base + QBF + SBF + RNQ + PL);
        float* P2  = (float*)(base + QBF + SBF + RNQ + 2 * PL);
        prep_all<<<1536, 256, 0, stream>>>(Q, S, Qbf, Sbf, rnq);
        knn_main<<<2560, 256, 0, stream>>>(Qbf, Sbf, P0, P1, P2);
        knn_merge<<<320, 1024, 0, stream>>>(P0, P1, P2, rnq, out);
    } else {
        float* rnq = (float*)d_ws;
        float* rns = rnq + 65536;
        float* partial = rns + 327680;
        norms_kernel<<<(65536 + 327680) / 256, 256, 0, stream>>>(Q, S, rnq, rns);
        knn_fb<<<dim3(2, 5, 64), 512, 0, stream>>>(Q, S, rnq, rns, partial);
        finalize2<<<2, 256, 0, stream>>>(partial, out);
    }
}